// Round 1
// 564.167 us; speedup vs baseline: 1.0218x; 1.0218x over previous
//
#include <hip/hip_runtime.h>
#include <hip/hip_bf16.h>

#define IN_CH 512
#define OUT_CH 512
#define W_DIM 512
#define BATCH 16
#define HWDIM 64
#define PADW 66

static constexpr float CONV_COEF = 0.014731391274719739f; // 1/sqrt(9*512)
static constexpr float FC_COEF   = 0.044194173824159216f; // 1/sqrt(512)

typedef __bf16 bf16x8 __attribute__((ext_vector_type(8)));
typedef float  f32x4  __attribute__((ext_vector_type(4)));

typedef __attribute__((address_space(1))) void gvoid;
typedef __attribute__((address_space(3))) void lvoid;

__device__ __forceinline__ void async_cp16(const void* g, void* l) {
    __builtin_amdgcn_global_load_lds((gvoid*)g, (lvoid*)l, 16, 0, 0);
}

__device__ __forceinline__ ushort f2bf(float f) {
    union { float f; unsigned u; } un; un.f = f;
    unsigned u = un.u;
    return (ushort)((u + 0x7fffu + ((u >> 16) & 1u)) >> 16);
}

// zero only the halo ring of xs (replaces 71 MB memset with 4.3 MB of stores)
__global__ void k_halo(ushort* __restrict__ xs) {
    int b = blockIdx.y;
    int pidx = blockIdx.x * 4 + (threadIdx.x >> 6);  // 0..259 exactly (65*4)
    int ch = threadIdx.x & 63;
    int h, w;
    if (pidx < 66)       { h = 0;          w = pidx; }
    else if (pidx < 132) { h = 65;         w = pidx - 66; }
    else if (pidx < 196) { h = pidx - 131; w = 0; }
    else                 { h = pidx - 195; w = 65; }
    size_t base = (((size_t)(b * PADW + h)) * PADW + w) * IN_CH + ch * 8;
    uint4 z = {0u, 0u, 0u, 0u};
    *(uint4*)(xs + base) = z;
}

// s[b,i] = (wl[b,:]·fcw[:,i])*FC_COEF + fcb[i] + 1   — grid (B,4) x 128 thr
__global__ void k_style(const float* __restrict__ wl, const float* __restrict__ fcw,
                        const float* __restrict__ fcb, float* __restrict__ s) {
    int b = blockIdx.x;
    int i = blockIdx.y * 128 + threadIdx.x;
    __shared__ float lw[W_DIM];
    for (int j = threadIdx.x; j < W_DIM; j += 128) lw[j] = wl[b * W_DIM + j];
    __syncthreads();
    float acc = 0.f;
#pragma unroll 8
    for (int j = 0; j < W_DIM; ++j) acc += lw[j] * fcw[(size_t)j * IN_CH + i];
    s[b * IN_CH + i] = acc * FC_COEF + fcb[i] + 1.0f;
}

// xs[b][h+1][w+1][c] = bf16(x[b,h,w,c] * s[b,c])
__global__ void k_xs(const float* __restrict__ x, const float* __restrict__ s,
                     ushort* __restrict__ xs) {
    int t = blockIdx.x * blockDim.x + threadIdx.x;  // one float4 per thread
    int pix = t >> 7;
    int c = (t & 127) << 2;
    int b = pix >> 12;
    int hw = pix & 4095;
    int h = hw >> 6, w = hw & 63;
    float4 xv = ((const float4*)x)[t];
    float4 sv = ((const float4*)(s + b * IN_CH))[t & 127];
    ushort4 o;
    o.x = f2bf(xv.x * sv.x);
    o.y = f2bf(xv.y * sv.y);
    o.z = f2bf(xv.z * sv.z);
    o.w = f2bf(xv.w * sv.w);
    size_t dst = (((size_t)(b * PADW + h + 1)) * PADW + (w + 1)) * IN_CH + c;
    *(ushort4*)(xs + dst) = o;
}

// wT[kk][out][in] = bf16(w[kk][in][out])
__global__ void k_wt(const float* __restrict__ w, ushort* __restrict__ wT) {
    __shared__ float tile[32][33];
    int kk = blockIdx.z;
    const float* src = w + (size_t)kk * IN_CH * OUT_CH;
    ushort* dst = wT + (size_t)kk * IN_CH * OUT_CH;
    int i0 = blockIdx.y * 32;
    int o0 = blockIdx.x * 32;
    int tx = threadIdx.x, ty = threadIdx.y;
#pragma unroll
    for (int rr = 0; rr < 32; rr += 8)
        tile[ty + rr][tx] = src[(size_t)(i0 + ty + rr) * OUT_CH + o0 + tx];
    __syncthreads();
#pragma unroll
    for (int rr = 0; rr < 32; rr += 8)
        dst[(size_t)(o0 + ty + rr) * IN_CH + i0 + tx] = f2bf(tile[tx][ty + rr]);
}

// a2[in*512+out] = sum_kk w[kk][in][out]^2
__global__ void k_a2(const float* __restrict__ w, float* __restrict__ a2) {
    int n = blockIdx.x * blockDim.x + threadIdx.x;
    float sum = 0.f;
#pragma unroll
    for (int kk = 0; kk < 9; ++kk) {
        float v = w[(size_t)kk * (IN_CH * OUT_CH) + n];
        sum += v * v;
    }
    a2[n] = sum;
}

// dmod[b,o] = rsqrt(coef^2 * sum_in a2[in,o]*s[b,in]^2 + 1e-8) — grid (B,4) x 128
__global__ void k_dmod(const float* __restrict__ s, const float* __restrict__ a2,
                       float* __restrict__ dmod) {
    int b = blockIdx.x;
    int o = blockIdx.y * 128 + threadIdx.x;
    __shared__ float s2[IN_CH];
    for (int i = threadIdx.x; i < IN_CH; i += 128) {
        float v = s[b * IN_CH + i];
        s2[i] = v * v;
    }
    __syncthreads();
    float acc = 0.f;
#pragma unroll 8
    for (int i = 0; i < IN_CH; ++i) acc += s2[i] * a2[(size_t)i * OUT_CH + o];
    dmod[b * OUT_CH + o] = rsqrtf(acc * CONV_COEF * CONV_COEF + 1e-8f);
}

// ---------------------------------------------------------------------------
// Implicit-GEMM conv, 256x256 tile pipeline (T1+T2+T3+T4+T5 stack):
//   M=65536 (b,h,w), N=512 (out), K=9*512. BM=BN=256, BK=64.
//   8 waves (2M x 4N), per-wave 128x64 output, acc[8][4] f32x4.
//   LDS: 2 x (A 256x64 + B 256x64) bf16 = 128 KiB, double-buffered.
//   Per K-step: 8 global_load_lds (4 A + 4 B) prefetched one step ahead;
//   s_waitcnt vmcnt(8) (never 0 in-loop) + raw s_barrier — the HBM latency
//   hides under the previous step's 64 MFMAs instead of a __syncthreads drain.
// ---------------------------------------------------------------------------

__device__ __forceinline__ int aoff_of(int t) {
    int kk = t >> 3;
    int c0 = (t & 7) << 6;
    int kh = (kk >= 6) ? 2 : ((kk >= 3) ? 1 : 0);
    int kw = kk - kh * 3;
    return (kh * PADW + kw) * IN_CH + c0;
}

__device__ __forceinline__ int boff_of(int t) {
    int kk = t >> 3;
    int c0 = (t & 7) << 6;
    return kk * (IN_CH * OUT_CH) + c0;
}

// 8 global_load_lds per wave: rows i*64+srow, phys chunk tid&7 holds logical
// chunk (tid&7)^(srow&7)  [bank swizzle; row&7 == srow&7 since i*64 % 8 == 0]
__device__ __forceinline__ void stage8(const ushort* gA, const ushort* gB,
                                       ushort* dA, ushort* dB) {
#pragma unroll
    for (int i = 0; i < 4; ++i) {
        async_cp16(gA + i * (PADW * IN_CH), dA + i * 4096);
        async_cp16(gB + i * (64 * IN_CH), dB + i * 4096);
    }
}

// one K-step: 2 ksub x 2 m-halves, 16 MFMA per cluster (64 total)
__device__ __forceinline__ void compute_step(
        const ushort* aB0, const ushort* aB1,
        const ushort* bB0, const ushort* bB1,
        f32x4 (&acc)[8][4]) {
#pragma unroll
    for (int ks = 0; ks < 2; ++ks) {
        const ushort* aB = ks ? aB1 : aB0;
        const ushort* bB = ks ? bB1 : bB0;
        bf16x8 bv[4];
#pragma unroll
        for (int j = 0; j < 4; ++j) bv[j] = *(const bf16x8*)(bB + j * 1024);
#pragma unroll
        for (int mh = 0; mh < 2; ++mh) {
            bf16x8 av[4];
#pragma unroll
            for (int f = 0; f < 4; ++f)
                av[f] = *(const bf16x8*)(aB + (mh * 4 + f) * 1024);
            __builtin_amdgcn_s_setprio(1);
#pragma unroll
            for (int i = 0; i < 4; ++i)
#pragma unroll
                for (int j = 0; j < 4; ++j)
                    acc[mh * 4 + i][j] = __builtin_amdgcn_mfma_f32_16x16x32_bf16(
                        av[i], bv[j], acc[mh * 4 + i][j], 0, 0, 0);
            __builtin_amdgcn_s_setprio(0);
        }
    }
}

__global__ __launch_bounds__(512, 2) void k_conv(
    const ushort* __restrict__ xs, const ushort* __restrict__ wT,
    const float* __restrict__ dmod, const float* __restrict__ bias,
    float* __restrict__ out) {
    __shared__ __align__(16) ushort smem[4][16384];  // A0,B0,A1,B1 — 128 KiB

    const int tid = threadIdx.x;
    const int wave = tid >> 6;
    const int lane = tid & 63;
    const int srow = tid >> 3;                 // staging row within 64-row slab
    const int lc = (tid & 7) ^ (srow & 7);     // pre-swizzled logical k-chunk

    // XCD swizzle (512 blocks, 512%8==0 → bijective): XCDs 0-3 get nt=0,
    // XCDs 4-7 get nt=1; each XCD holds one 2.4 MB B-panel in its L2 and a
    // contiguous mt range.
    const int wg = (blockIdx.x & 7) * 64 + (blockIdx.x >> 3);
    const int nt = wg >> 8;                    // 0..1
    const int mt = wg & 255;                   // 0..255
    const int b  = mt >> 4;
    const int h0 = (mt & 15) << 2;             // 4 h-rows per M-tile
    const int n0 = nt << 8;

    // A row r = i*64 + srow → rh = i, w = srow (exact since srow < 64)
    const ushort* gA0 = xs + (((size_t)(b * PADW + h0)) * PADW + srow) * IN_CH + lc * 8;
    const ushort* gB0 = wT + ((size_t)(n0 + srow)) * IN_CH + lc * 8;

    ushort* dA[2] = { &smem[0][wave * 512], &smem[2][wave * 512] };
    ushort* dB[2] = { &smem[1][wave * 512], &smem[3][wave * 512] };

    const int rlane = lane & 15;
    const int q = lane >> 4;
    const int wm = wave >> 2;                  // 0..1 (M half)
    const int wn = wave & 3;                   // 0..3 (N quarter)
    // frag read: row&7 == rlane&7 for every fragment → 2 base ptrs per operand
    const int pc0 = ((q + 0) ^ (rlane & 7)) * 8;
    const int pc1 = ((q + 4) ^ (rlane & 7)) * 8;

    const ushort* aR[2][2];
    const ushort* bR[2][2];
#pragma unroll
    for (int bf = 0; bf < 2; ++bf) {
        aR[bf][0] = &smem[bf * 2][(wm * 128 + rlane) * 64 + pc0];
        aR[bf][1] = &smem[bf * 2][(wm * 128 + rlane) * 64 + pc1];
        bR[bf][0] = &smem[bf * 2 + 1][(wn * 64 + rlane) * 64 + pc0];
        bR[bf][1] = &smem[bf * 2 + 1][(wn * 64 + rlane) * 64 + pc1];
    }

    f32x4 acc[8][4];
#pragma unroll
    for (int i = 0; i < 8; ++i)
#pragma unroll
        for (int j = 0; j < 4; ++j) {
            f32x4 z = {0.f, 0.f, 0.f, 0.f};
            acc[i][j] = z;
        }

    // prologue: stage t=0 into buf0
    stage8(gA0 + aoff_of(0), gB0 + boff_of(0), dA[0], dB[0]);

#pragma unroll 1
    for (int t = 0; t < 72; t += 2) {
        // issue t+1 into buf1 (t+1 <= 71 always), then wait only for t's 8
        stage8(gA0 + aoff_of(t + 1), gB0 + boff_of(t + 1), dA[1], dB[1]);
        asm volatile("s_waitcnt vmcnt(8)" ::: "memory");
        __builtin_amdgcn_s_barrier();
        asm volatile("" ::: "memory");
        compute_step(aR[0][0], aR[0][1], bR[0][0], bR[0][1], acc);
        asm volatile("" ::: "memory");
        __builtin_amdgcn_s_barrier();   // all reads of buf0 done → safe to overwrite
        asm volatile("" ::: "memory");

        if (t + 2 < 72) {
            stage8(gA0 + aoff_of(t + 2), gB0 + boff_of(t + 2), dA[0], dB[0]);
            asm volatile("s_waitcnt vmcnt(8)" ::: "memory");
        } else {
            asm volatile("s_waitcnt vmcnt(0)" ::: "memory");  // epilogue drain
        }
        __builtin_amdgcn_s_barrier();
        asm volatile("" ::: "memory");
        compute_step(aR[1][0], aR[1][1], bR[1][0], bR[1][1], acc);
        asm volatile("" ::: "memory");
        __builtin_amdgcn_s_barrier();
        asm volatile("" ::: "memory");
    }

    // epilogue: C/D layout col=lane&15 (n), row=(lane>>4)*4+reg (m)
#pragma unroll
    for (int j = 0; j < 4; ++j) {
        const int n = n0 + wn * 64 + j * 16 + rlane;
        const float scale = dmod[b * OUT_CH + n] * CONV_COEF;
        const float bv2 = bias[n];
#pragma unroll
        for (int i = 0; i < 8; ++i) {
#pragma unroll
            for (int e = 0; e < 4; ++e) {
                const int m = wm * 128 + i * 16 + q * 4 + e;
                const int h = h0 + (m >> 6);
                const int w = m & 63;
                out[(((size_t)(b * HWDIM + h)) * HWDIM + w) * OUT_CH + n] =
                    acc[i][j][e] * scale + bv2;
            }
        }
    }
}

extern "C" void kernel_launch(void* const* d_in, const int* in_sizes, int n_in,
                              void* d_out, int out_size, void* d_ws, size_t ws_size,
                              hipStream_t stream) {
    const float* x    = (const float*)d_in[0];
    const float* wl   = (const float*)d_in[1];
    const float* w    = (const float*)d_in[2];
    const float* bias = (const float*)d_in[3];
    const float* fcw  = (const float*)d_in[4];
    const float* fcb  = (const float*)d_in[5];
    float* out = (float*)d_out;

    char* ws = (char*)d_ws;
    const size_t XS_BYTES = (size_t)BATCH * PADW * PADW * IN_CH * 2;  // 71,368,704
    const size_t WT_BYTES = (size_t)9 * IN_CH * OUT_CH * 2;           //  4,718,592
    ushort* xs   = (ushort*)ws;
    ushort* wT   = (ushort*)(ws + XS_BYTES);
    float*  s    = (float*)(ws + XS_BYTES + WT_BYTES);
    float*  dmod = s + BATCH * IN_CH;
    float*  a2   = dmod + BATCH * OUT_CH;

    k_halo<<<dim3(65, BATCH), 256, 0, stream>>>(xs);
    k_style<<<dim3(BATCH, 4), 128, 0, stream>>>(wl, fcw, fcb, s);
    k_xs<<<(BATCH * HWDIM * HWDIM * IN_CH / 4) / 256, 256, 0, stream>>>(x, s, xs);
    k_wt<<<dim3(16, 16, 9), dim3(32, 8), 0, stream>>>(w, wT);
    k_a2<<<(IN_CH * OUT_CH) / 256, 256, 0, stream>>>(w, a2);
    k_dmod<<<dim3(BATCH, 4), 128, 0, stream>>>(s, a2, dmod);
    k_conv<<<512, 512, 0, stream>>>(xs, wT, dmod, bias, out);
}

// Round 3
// 549.508 us; speedup vs baseline: 1.0491x; 1.0267x over previous
//
#include <hip/hip_runtime.h>
#include <hip/hip_bf16.h>

#define IN_CH 512
#define OUT_CH 512
#define W_DIM 512
#define BATCH 16
#define HWDIM 64
#define PADW 66

static constexpr float CONV_COEF = 0.014731391274719739f; // 1/sqrt(9*512)
static constexpr float FC_COEF   = 0.044194173824159216f; // 1/sqrt(512)

typedef __bf16 bf16x8 __attribute__((ext_vector_type(8)));
typedef float  f32x4  __attribute__((ext_vector_type(4)));

typedef __attribute__((address_space(1))) void gvoid;
typedef __attribute__((address_space(3))) void lvoid;

__device__ __forceinline__ void async_cp16(const void* g, void* l) {
    __builtin_amdgcn_global_load_lds((gvoid*)g, (lvoid*)l, 16, 0, 0);
}

__device__ __forceinline__ ushort f2bf(float f) {
    union { float f; unsigned u; } un; un.f = f;
    unsigned u = un.u;
    return (ushort)((u + 0x7fffu + ((u >> 16) & 1u)) >> 16);
}

// zero only the halo ring of xs (replaces 71 MB memset with 4.3 MB of stores)
__global__ void k_halo(ushort* __restrict__ xs) {
    int b = blockIdx.y;
    int pidx = blockIdx.x * 4 + (threadIdx.x >> 6);  // 0..259 exactly (65*4)
    int ch = threadIdx.x & 63;
    int h, w;
    if (pidx < 66)       { h = 0;          w = pidx; }
    else if (pidx < 132) { h = 65;         w = pidx - 66; }
    else if (pidx < 196) { h = pidx - 131; w = 0; }
    else                 { h = pidx - 195; w = 65; }
    size_t base = (((size_t)(b * PADW + h)) * PADW + w) * IN_CH + ch * 8;
    uint4 z = {0u, 0u, 0u, 0u};
    *(uint4*)(xs + base) = z;
}

// s[b,i] = (wl[b,:]·fcw[:,i])*FC_COEF + fcb[i] + 1   — grid (B,4) x 128 thr
__global__ void k_style(const float* __restrict__ wl, const float* __restrict__ fcw,
                        const float* __restrict__ fcb, float* __restrict__ s) {
    int b = blockIdx.x;
    int i = blockIdx.y * 128 + threadIdx.x;
    __shared__ float lw[W_DIM];
    for (int j = threadIdx.x; j < W_DIM; j += 128) lw[j] = wl[b * W_DIM + j];
    __syncthreads();
    float acc = 0.f;
#pragma unroll 8
    for (int j = 0; j < W_DIM; ++j) acc += lw[j] * fcw[(size_t)j * IN_CH + i];
    s[b * IN_CH + i] = acc * FC_COEF + fcb[i] + 1.0f;
}

// xs[b][h+1][w+1][c] = bf16(x[b,h,w,c] * s[b,c])
__global__ void k_xs(const float* __restrict__ x, const float* __restrict__ s,
                     ushort* __restrict__ xs) {
    int t = blockIdx.x * blockDim.x + threadIdx.x;  // one float4 per thread
    int pix = t >> 7;
    int c = (t & 127) << 2;
    int b = pix >> 12;
    int hw = pix & 4095;
    int h = hw >> 6, w = hw & 63;
    float4 xv = ((const float4*)x)[t];
    float4 sv = ((const float4*)(s + b * IN_CH))[t & 127];
    ushort4 o;
    o.x = f2bf(xv.x * sv.x);
    o.y = f2bf(xv.y * sv.y);
    o.z = f2bf(xv.z * sv.z);
    o.w = f2bf(xv.w * sv.w);
    size_t dst = (((size_t)(b * PADW + h + 1)) * PADW + (w + 1)) * IN_CH + c;
    *(ushort4*)(xs + dst) = o;
}

// wT[kk][out][in] = bf16(w[kk][in][out])
__global__ void k_wt(const float* __restrict__ w, ushort* __restrict__ wT) {
    __shared__ float tile[32][33];
    int kk = blockIdx.z;
    const float* src = w + (size_t)kk * IN_CH * OUT_CH;
    ushort* dst = wT + (size_t)kk * IN_CH * OUT_CH;
    int i0 = blockIdx.y * 32;
    int o0 = blockIdx.x * 32;
    int tx = threadIdx.x, ty = threadIdx.y;
#pragma unroll
    for (int rr = 0; rr < 32; rr += 8)
        tile[ty + rr][tx] = src[(size_t)(i0 + ty + rr) * OUT_CH + o0 + tx];
    __syncthreads();
#pragma unroll
    for (int rr = 0; rr < 32; rr += 8)
        dst[(size_t)(o0 + ty + rr) * IN_CH + i0 + tx] = f2bf(tile[tx][ty + rr]);
}

// a2[in*512+out] = sum_kk w[kk][in][out]^2
__global__ void k_a2(const float* __restrict__ w, float* __restrict__ a2) {
    int n = blockIdx.x * blockDim.x + threadIdx.x;
    float sum = 0.f;
#pragma unroll
    for (int kk = 0; kk < 9; ++kk) {
        float v = w[(size_t)kk * (IN_CH * OUT_CH) + n];
        sum += v * v;
    }
    a2[n] = sum;
}

// dmod[b,o] = rsqrt(coef^2 * sum_in a2[in,o]*s[b,in]^2 + 1e-8) — grid (B,4) x 128
__global__ void k_dmod(const float* __restrict__ s, const float* __restrict__ a2,
                       float* __restrict__ dmod) {
    int b = blockIdx.x;
    int o = blockIdx.y * 128 + threadIdx.x;
    __shared__ float s2[IN_CH];
    for (int i = threadIdx.x; i < IN_CH; i += 128) {
        float v = s[b * IN_CH + i];
        s2[i] = v * v;
    }
    __syncthreads();
    float acc = 0.f;
#pragma unroll 8
    for (int i = 0; i < IN_CH; ++i) acc += s2[i] * a2[(size_t)i * OUT_CH + o];
    dmod[b * OUT_CH + o] = rsqrtf(acc * CONV_COEF * CONV_COEF + 1e-8f);
}

// ---------------------------------------------------------------------------
// Implicit-GEMM conv, 256x256 tile, 4-phase-per-K-step pipeline (m201 port):
//   M=65536, N=512, K=4608. BM=BN=256, BK=64, 8 waves (2M x 4N), 128 KiB LDS.
//   Per K-step, 4 phases of 16 MFMA: {ds_read own operands, stage 4 loads
//   (phases 0-1), barrier, setprio(1), MFMA x16, setprio(0), barrier}.
//   Barrier-slip + setprio overlap one wave's ds_read phase with another's
//   MFMA cluster (T3+T5); vmcnt(0) for next-tile staging sits at end of
//   phase 3, ~1800 cyc after issue — effectively free (T4 discipline).
// ---------------------------------------------------------------------------

__device__ __forceinline__ int aoff_of(int t) {
    int kk = t >> 3;
    int c0 = (t & 7) << 6;
    int kh = (kk >= 6) ? 2 : ((kk >= 3) ? 1 : 0);
    int kw = kk - kh * 3;
    return (kh * PADW + kw) * IN_CH + c0;
}

__device__ __forceinline__ int boff_of(int t) {
    int kk = t >> 3;
    int c0 = (t & 7) << 6;
    return kk * (IN_CH * OUT_CH) + c0;
}

__device__ __forceinline__ void bar() {
    asm volatile("" ::: "memory");
    __builtin_amdgcn_s_barrier();
    asm volatile("" ::: "memory");
}

#define MFMA16(AV, MH)                                                        \
    __builtin_amdgcn_s_setprio(1);                                            \
    _Pragma("unroll")                                                         \
    for (int i = 0; i < 4; ++i)                                               \
        _Pragma("unroll")                                                     \
        for (int j = 0; j < 4; ++j)                                           \
            acc[(MH)*4 + i][j] = __builtin_amdgcn_mfma_f32_16x16x32_bf16(     \
                AV[i], bv[j], acc[(MH)*4 + i][j], 0, 0, 0);                   \
    __builtin_amdgcn_s_setprio(0);

// one K-step = 4 phases; reads from (aBase,bBase); stages t+1 into (dA,dB)
__device__ __forceinline__ void step4(
    const ushort* __restrict__ aBase, const ushort* __restrict__ bBase,
    int pc0, int pc1,
    const ushort* __restrict__ gA, const ushort* __restrict__ gB,
    ushort* __restrict__ dA, ushort* __restrict__ dB,
    bool doStage, f32x4 (&acc)[8][4])
{
    bf16x8 av[4], bv[4];

    // ---- P0: B[ks0] + A[mh0][ks0]; stage A-half of next tile
#pragma unroll
    for (int f = 0; f < 4; ++f) bv[f] = *(const bf16x8*)(bBase + f * 1024 + pc0);
#pragma unroll
    for (int f = 0; f < 4; ++f) av[f] = *(const bf16x8*)(aBase + f * 1024 + pc0);
    if (doStage) {
#pragma unroll
        for (int i = 0; i < 4; ++i)
            async_cp16(gA + i * (PADW * IN_CH), dA + i * 4096);
    }
    bar();
    MFMA16(av, 0)
    bar();

    // ---- P1: A[mh1][ks0] (reuse bv); stage B-half of next tile
#pragma unroll
    for (int f = 0; f < 4; ++f) av[f] = *(const bf16x8*)(aBase + 4096 + f * 1024 + pc0);
    if (doStage) {
#pragma unroll
        for (int i = 0; i < 4; ++i)
            async_cp16(gB + i * (64 * IN_CH), dB + i * 4096);
    }
    bar();
    MFMA16(av, 1)
    bar();

    // ---- P2: B[ks1] + A[mh0][ks1]
#pragma unroll
    for (int f = 0; f < 4; ++f) bv[f] = *(const bf16x8*)(bBase + f * 1024 + pc1);
#pragma unroll
    for (int f = 0; f < 4; ++f) av[f] = *(const bf16x8*)(aBase + f * 1024 + pc1);
    bar();
    MFMA16(av, 0)
    bar();

    // ---- P3: A[mh1][ks1]; vmcnt(0) drains next-tile staging (issued ~3
    //      phases ago) before the step-final barrier
#pragma unroll
    for (int f = 0; f < 4; ++f) av[f] = *(const bf16x8*)(aBase + 4096 + f * 1024 + pc1);
    bar();
    MFMA16(av, 1)
    asm volatile("s_waitcnt vmcnt(0)" ::: "memory");
    bar();
}

__global__ __launch_bounds__(512, 2) void k_conv(
    const ushort* __restrict__ xs, const ushort* __restrict__ wT,
    const float* __restrict__ dmod, const float* __restrict__ bias,
    float* __restrict__ out) {
    __shared__ __align__(16) ushort smem[4][16384];  // A0,B0,A1,B1 — 128 KiB

    const int tid = threadIdx.x;
    const int wave = tid >> 6;
    const int lane = tid & 63;
    const int srow = tid >> 3;                 // staging row within 64-row slab
    const int lc = (tid & 7) ^ (srow & 7);     // pre-swizzled logical k-chunk

    // XCD swizzle (512 blocks, 512%8==0 → bijective)
    const int wg = (blockIdx.x & 7) * 64 + (blockIdx.x >> 3);
    const int nt = wg >> 8;                    // 0..1
    const int mt = wg & 255;                   // 0..255
    const int b  = mt >> 4;
    const int h0 = (mt & 15) << 2;             // 4 h-rows per M-tile
    const int n0 = nt << 8;

    const ushort* gA0 = xs + (((size_t)(b * PADW + h0)) * PADW + srow) * IN_CH + lc * 8;
    const ushort* gB0 = wT + ((size_t)(n0 + srow)) * IN_CH + lc * 8;

    ushort* dA[2] = { &smem[0][wave * 512], &smem[2][wave * 512] };
    ushort* dB[2] = { &smem[1][wave * 512], &smem[3][wave * 512] };

    const int rlane = lane & 15;
    const int q = lane >> 4;
    const int wm = wave >> 2;                  // 0..1 (M half)
    const int wn = wave & 3;                   // 0..3 (N quarter)
    const int pc0 = ((q + 0) ^ (rlane & 7)) * 8;
    const int pc1 = ((q + 4) ^ (rlane & 7)) * 8;

    const ushort* aBase[2] = {
        &smem[0][(wm * 128 + rlane) * 64],
        &smem[2][(wm * 128 + rlane) * 64],
    };
    const ushort* bBase[2] = {
        &smem[1][(wn * 64 + rlane) * 64],
        &smem[3][(wn * 64 + rlane) * 64],
    };

    f32x4 acc[8][4];
#pragma unroll
    for (int i = 0; i < 8; ++i)
#pragma unroll
        for (int j = 0; j < 4; ++j) {
            f32x4 z = {0.f, 0.f, 0.f, 0.f};
            acc[i][j] = z;
        }

    // prologue: stage t=0 into buf0
#pragma unroll
    for (int i = 0; i < 4; ++i) {
        async_cp16(gA0 + aoff_of(0) + i * (PADW * IN_CH), dA[0] + i * 4096);
        async_cp16(gB0 + boff_of(0) + i * (64 * IN_CH), dB[0] + i * 4096);
    }
    asm volatile("s_waitcnt vmcnt(0)" ::: "memory");
    bar();

#pragma unroll 1
    for (int t = 0; t < 72; t += 2) {
        // step t from buf0, staging t+1 into buf1 (t+1 <= 71 always)
        step4(aBase[0], bBase[0], pc0, pc1,
              gA0 + aoff_of(t + 1), gB0 + boff_of(t + 1),
              dA[1], dB[1], true, acc);
        // step t+1 from buf1, staging t+2 into buf0
        step4(aBase[1], bBase[1], pc0, pc1,
              gA0 + aoff_of(t + 2), gB0 + boff_of(t + 2),
              dA[0], dB[0], (t + 2 < 72), acc);
    }

    // epilogue: C/D layout col=lane&15 (n), row=(lane>>4)*4+reg (m)
#pragma unroll
    for (int j = 0; j < 4; ++j) {
        const int n = n0 + wn * 64 + j * 16 + rlane;
        const float scale = dmod[b * OUT_CH + n] * CONV_COEF;
        const float bv2 = bias[n];
#pragma unroll
        for (int i = 0; i < 8; ++i) {
#pragma unroll
            for (int e = 0; e < 4; ++e) {
                const int m = wm * 128 + i * 16 + q * 4 + e;
                const int h = h0 + (m >> 6);
                const int w = m & 63;
                out[(((size_t)(b * HWDIM + h)) * HWDIM + w) * OUT_CH + n] =
                    acc[i][j][e] * scale + bv2;
            }
        }
    }
}

extern "C" void kernel_launch(void* const* d_in, const int* in_sizes, int n_in,
                              void* d_out, int out_size, void* d_ws, size_t ws_size,
                              hipStream_t stream) {
    const float* x    = (const float*)d_in[0];
    const float* wl   = (const float*)d_in[1];
    const float* w    = (const float*)d_in[2];
    const float* bias = (const float*)d_in[3];
    const float* fcw  = (const float*)d_in[4];
    const float* fcb  = (const float*)d_in[5];
    float* out = (float*)d_out;

    char* ws = (char*)d_ws;
    const size_t XS_BYTES = (size_t)BATCH * PADW * PADW * IN_CH * 2;  // 71,368,704
    const size_t WT_BYTES = (size_t)9 * IN_CH * OUT_CH * 2;           //  4,718,592
    ushort* xs   = (ushort*)ws;
    ushort* wT   = (ushort*)(ws + XS_BYTES);
    float*  s    = (float*)(ws + XS_BYTES + WT_BYTES);
    float*  dmod = s + BATCH * IN_CH;
    float*  a2   = dmod + BATCH * OUT_CH;

    k_halo<<<dim3(65, BATCH), 256, 0, stream>>>(xs);
    k_style<<<dim3(BATCH, 4), 128, 0, stream>>>(wl, fcw, fcb, s);
    k_xs<<<(BATCH * HWDIM * HWDIM * IN_CH / 4) / 256, 256, 0, stream>>>(x, s, xs);
    k_wt<<<dim3(16, 16, 9), dim3(32, 8), 0, stream>>>(w, wT);
    k_a2<<<(IN_CH * OUT_CH) / 256, 256, 0, stream>>>(w, a2);
    k_dmod<<<dim3(BATCH, 4), 128, 0, stream>>>(s, a2, dmod);
    k_conv<<<512, 512, 0, stream>>>(xs, wT, dmod, bias, out);
}